// Round 11
// baseline (68.837 us; speedup 1.0000x reference)
//
#include <hip/hip_runtime.h>

typedef _Float16 f16;
typedef __attribute__((ext_vector_type(8))) _Float16 f16x8;
typedef __attribute__((ext_vector_type(4))) _Float16 f16x4;
typedef __attribute__((ext_vector_type(4))) float f32x4;

#define MFMA16(a, b, c) __builtin_amdgcn_mfma_f32_16x16x32_f16(a, b, c, 0, 0, 0)

#define B_N 16384
#define E_N 9
#define TILE 48
#define NT_GRID 352   // 8*44 >= max tiles (341+9); exact XCD swizzle
#define THREADS 512

#define D_IN 512
#define D_H1 512
#define D_H2 256
#define D_H3 128
#define D_A 16

// Weight image: per (e,w) 104 contiguous 1KB B-fragment records, k-major order.
// Record r at ((e*8+w)*104+r)*1024; lane l's 16B at +l*16; lane holds (n,k[8]).
//   r<64  (L1): kk=r>>2, nf=r&3:  n=w*64+nf*16+ln, k=kk*32+lg*8   (W1: 512x512)
//   64..95(L2): j=r-64,kk=j>>1,nf=j&1: n=w*32+nf*16+ln, k=kk*32+lg*8 (W2: 256x512)
//   96..103(L3): kk=r-96:         n=w*16+ln,       k=kk*32+lg*8   (W3: 128x256)
// L4: plain [16n][128k] per expert (4KB) at O4B.
#define RPW 104
#define O4B 7667712
#define WPL_BYTES 7704576
#define WSLOTS (WPL_BYTES / 16)

#define IDX_OFF 64
#define WP_OFF 131584
#define WS_NEED (WP_OFF + (size_t)WPL_BYTES)

// LDS (bytes) -- 72KB -> 2 blocks/CU.
// x/h1 [48][1024B] at 0..48K (swz (row&15)<<4); h1 overwrites x after L1.
// h2   [48][512B]  at 48K..72K (dedicated).
// h3   [48][256B]  at 0..12K (overlays x/h1 after L2 barrier).
#define H2_OFF 49152
#define LDS_BYTES 73728

// ---------------- bucketing (proven-fast) ----------------

__global__ void k_bucket(const int* __restrict__ pos, int* __restrict__ hdr,
                         int* __restrict__ idx) {
  __shared__ int cnt[E_N], cur[E_N];
  __shared__ int flag_s;
  const int t = threadIdx.x;  // 1024
  if (t < E_N) cnt[t] = 0;
  if (t == 0) {
    int nz = 0;
    for (int i = 0; i < 64; ++i) nz |= pos[2 * i + 1];
    flag_s = (nz == 0) ? 1 : 0;  // int64 layout if all high words zero
  }
  __syncthreads();
  const bool f64 = flag_s != 0;
  int e[16];
#pragma unroll
  for (int k = 0; k < 16; ++k) {
    int i = k * 1024 + t;
    long long v = f64 ? ((const long long*)pos)[i] : (long long)pos[i];
    v = v < 0 ? 0 : (v > 8 ? 8 : v);
    e[k] = (int)v;
    atomicAdd(&cnt[e[k]], 1);
  }
  __syncthreads();
  if (t == 0) {
    int acc = 0;
    for (int ee = 0; ee < E_N; ++ee) { cur[ee] = acc; acc += cnt[ee]; }
  }
  if (t < E_N) hdr[8 + t] = cnt[t];
  __syncthreads();
#pragma unroll
  for (int k = 0; k < 16; ++k) {
    int i = k * 1024 + t;
    int slot = atomicAdd(&cur[e[k]], 1);
    idx[slot] = i;
  }
}

// ---------------- weight convert fp32 -> k-major fragment image ----------------

__global__ void k_wcvt(const float* __restrict__ W1, const float* __restrict__ W2,
                       const float* __restrict__ W3, const float* __restrict__ W4,
                       char* __restrict__ wp) {
  int slot = blockIdx.x * 256 + threadIdx.x;
  if (slot >= WSLOTS) return;
  long addr = (long)slot << 4;
  int lane = slot & 63;
  int lg = lane >> 4, ln = lane & 15;
  const float* src;
  if (addr < O4B) {
    int rec = (int)(addr >> 10);
    int f = rec % RPW;
    int ew = rec / RPW;
    int w = ew & 7, e = ew >> 3;
    if (f < 64) {
      int kk = f >> 2, nf = f & 3;
      int n = w * 64 + nf * 16 + ln;
      int k = kk * 32 + lg * 8;
      src = W1 + ((long)e * D_H1 + n) * D_IN + k;
    } else if (f < 96) {
      int j = f - 64;
      int kk = j >> 1, nf = j & 1;
      int n = w * 32 + nf * 16 + ln;
      int k = kk * 32 + lg * 8;
      src = W2 + ((long)e * D_H2 + n) * D_H1 + k;
    } else {
      int kk = f - 96;
      int n = w * 16 + ln;
      int k = kk * 32 + lg * 8;
      src = W3 + ((long)e * D_H3 + n) * D_H2 + k;
    }
  } else {
    long rel = addr - O4B;
    int e = (int)(rel >> 12);
    int r2 = (int)(rel & 4095);
    int s = r2 >> 4, n = s >> 4, k16 = s & 15;
    src = W4 + ((long)e * D_A + n) * D_H3 + k16 * 8;
  }
  float4 a = *(const float4*)src;
  float4 b = *(const float4*)(src + 4);
  f16x8 h;
  h[0] = (f16)a.x; h[1] = (f16)a.y; h[2] = (f16)a.z; h[3] = (f16)a.w;
  h[4] = (f16)b.x; h[5] = (f16)b.y; h[6] = (f16)b.z; h[7] = (f16)b.w;
  *(f16x8*)(wp + addr) = h;
}

// ---------------- fused MLP ----------------

__device__ __forceinline__ f16x8 afrag(const char* base, int strideB, int rowoff,
                                       int kbytes, int lane) {
  int m = rowoff + (lane & 15);
  int q = kbytes + ((lane >> 4) * 16);
  return *(const f16x8*)(base + m * strideB + (q ^ ((m & 15) << 4)));
}

__device__ __forceinline__ f16x8 ldfrag(const char* wb, int f, int lane) {
  return *(const f16x8*)(wb + (long)f * 1024 + lane * 16);
}

__launch_bounds__(THREADS, 2)  // unpin registers (R10: (512,4) pinned 64 -> 16MB spill)
__global__ void k_mlp(const float* __restrict__ x,
                      const float* __restrict__ b1, const float* __restrict__ b2,
                      const float* __restrict__ b3, const float* __restrict__ b4,
                      const int* __restrict__ hdr, const int* __restrict__ idx,
                      const char* __restrict__ wp, float* __restrict__ out) {
  __shared__ __align__(16) char lds[LDS_BYTES];

  int b = blockIdx.x;
  int bswz = (b & 7) * (NT_GRID / 8) + (b >> 3);  // bijective on [0,352)

  const int* counts = hdr + 8;
  int e = -1, tile = 0, base = 0, ne = 0;
  {
    int acc = 0, off = 0;
    for (int ee = 0; ee < E_N; ++ee) {
      int n = counts[ee];
      int nt = (n + TILE - 1) / TILE;
      if (bswz < acc + nt) { e = ee; tile = bswz - acc; ne = n; base = off; break; }
      acc += nt; off += n;
    }
  }
  if (e < 0) return;
  const int rvalid = min(TILE, ne - tile * TILE);
  const int row0 = base + tile * TILE;

  const int t = threadIdx.x;
  const int lane = t & 63;
  const int wid = t >> 6;
  const int lg = lane >> 4;
  const int ln = lane & 15;

  const char* wb = wp + ((long)(e * 8 + wid) * RPW << 10);
  const char* wpe4 = wp + O4B + (long)e * 4096;

  // depth-8 queue over the flat 104-record k-major stream
  f16x8 Q[8];
#pragma unroll
  for (int i = 0; i < 8; ++i) Q[i] = ldfrag(wb, i, lane);

  // ---- stage x tile (48 rows) as fp16, XOR-swizzled ----
  const float4* x4 = (const float4*)x;
#pragma unroll
  for (int v8 = 0; v8 < 12; ++v8) {
    int u = v8 * THREADS + t;              // 6144 = 48*128 float4s
    int s = u >> 7, c4 = u & 127;
    float4 v = make_float4(0.f, 0.f, 0.f, 0.f);
    if (s < rvalid) v = x4[(long)idx[row0 + s] * (D_IN / 4) + c4];
    f16x4 h;
    h[0] = (f16)v.x; h[1] = (f16)v.y; h[2] = (f16)v.z; h[3] = (f16)v.w;
    *(f16x4*)(lds + s * 1024 + ((c4 * 8) ^ ((s & 15) << 4))) = h;
  }
  __syncthreads();

  // ---------------- L1: h1[48x512] = x @ W1^T (recs 0..63, kk=ss) ----------------
  {
    f32x4 acc1[3][4];
#pragma unroll
    for (int m = 0; m < 3; ++m)
#pragma unroll
      for (int r = 0; r < 4; ++r) acc1[m][r] = (f32x4){0.f, 0.f, 0.f, 0.f};

#pragma unroll
    for (int ss = 0; ss < 16; ++ss) {
      f16x8 A0 = afrag(lds, 1024, 0, ss * 64, lane);
      f16x8 A1 = afrag(lds, 1024, 16, ss * 64, lane);
      f16x8 A2 = afrag(lds, 1024, 32, ss * 64, lane);
      __builtin_amdgcn_s_setprio(1);
#pragma unroll
      for (int r = 0; r < 4; ++r) {
        const int i = ss * 4 + r;
        acc1[0][r] = MFMA16(A0, Q[i & 7], acc1[0][r]);
        acc1[1][r] = MFMA16(A1, Q[i & 7], acc1[1][r]);
        acc1[2][r] = MFMA16(A2, Q[i & 7], acc1[2][r]);
        Q[i & 7] = ldfrag(wb, i + 8, lane);  // i<=63 -> i+8<=71
      }
      __builtin_amdgcn_s_setprio(0);
      __builtin_amdgcn_sched_barrier(0);
    }
    __syncthreads();  // all L1 reads of x done; x region dead

    // write h1 = relu(acc+bias) into x region [48][1024B]
#pragma unroll
    for (int nf = 0; nf < 4; ++nf) {
      int n = wid * 64 + nf * 16 + ln;
      float bias = b1[e * D_H1 + n];
#pragma unroll
      for (int m = 0; m < 3; ++m)
#pragma unroll
        for (int j = 0; j < 4; ++j) {
          float v = acc1[m][nf][j] + bias;
          v = v > 0.f ? v : 0.f;
          int rw = m * 16 + lg * 4 + j;
          *(f16*)(lds + rw * 1024 + ((n * 2) ^ ((rw & 15) << 4))) = (f16)v;
        }
    }
  }
  __syncthreads();

  // ---------------- L2: h2[48x256] = h1 @ W2^T (recs 64..95) ----------------
  {
    f32x4 acc2[3][2];
#pragma unroll
    for (int m = 0; m < 3; ++m)
#pragma unroll
      for (int nf = 0; nf < 2; ++nf) acc2[m][nf] = (f32x4){0.f, 0.f, 0.f, 0.f};

#pragma unroll
    for (int ss = 16; ss < 24; ++ss) {
#pragma unroll
      for (int hh = 0; hh < 2; ++hh) {
        const int kk = (ss - 16) * 2 + hh;
        f16x8 A0 = afrag(lds, 1024, 0, kk * 64, lane);
        f16x8 A1 = afrag(lds, 1024, 16, kk * 64, lane);
        f16x8 A2 = afrag(lds, 1024, 32, kk * 64, lane);
        __builtin_amdgcn_s_setprio(1);
#pragma unroll
        for (int nf = 0; nf < 2; ++nf) {
          const int i = ss * 4 + hh * 2 + nf;  // = 64 + kk*2 + nf
          acc2[0][nf] = MFMA16(A0, Q[i & 7], acc2[0][nf]);
          acc2[1][nf] = MFMA16(A1, Q[i & 7], acc2[1][nf]);
          acc2[2][nf] = MFMA16(A2, Q[i & 7], acc2[2][nf]);
          if (i < 96) Q[i & 7] = ldfrag(wb, i + 8, lane);  // up to rec 103
        }
        __builtin_amdgcn_s_setprio(0);
      }
      __builtin_amdgcn_sched_barrier(0);
    }
    // h2 region is dedicated: direct write, no pre-barrier
#pragma unroll
    for (int nf = 0; nf < 2; ++nf) {
      int n = wid * 32 + nf * 16 + ln;
      float bias = b2[e * D_H2 + n];
#pragma unroll
      for (int m = 0; m < 3; ++m)
#pragma unroll
        for (int j = 0; j < 4; ++j) {
          float v = acc2[m][nf][j] + bias;
          v = v > 0.f ? v : 0.f;
          int rw = m * 16 + lg * 4 + j;
          *(f16*)(lds + H2_OFF + rw * 512 + ((n * 2) ^ ((rw & 15) << 4))) = (f16)v;
        }
    }
  }
  __syncthreads();

  // ---------------- L3: h3[48x128] = h2 @ W3^T (recs 96..103, in Q) ----------------
  {
    f32x4 acc3[3];
#pragma unroll
    for (int m = 0; m < 3; ++m) acc3[m] = (f32x4){0.f, 0.f, 0.f, 0.f};
    __builtin_amdgcn_s_setprio(1);
#pragma unroll
    for (int kk = 0; kk < 8; ++kk) {
      const int i = 96 + kk;
      f16x8 A0 = afrag(lds + H2_OFF, 512, 0, kk * 64, lane);
      f16x8 A1 = afrag(lds + H2_OFF, 512, 16, kk * 64, lane);
      f16x8 A2 = afrag(lds + H2_OFF, 512, 32, kk * 64, lane);
      acc3[0] = MFMA16(A0, Q[i & 7], acc3[0]);
      acc3[1] = MFMA16(A1, Q[i & 7], acc3[1]);
      acc3[2] = MFMA16(A2, Q[i & 7], acc3[2]);
    }
    __builtin_amdgcn_s_setprio(0);
    int n = wid * 16 + ln;
    float bias = b3[e * D_H3 + n];
    // h3 [48][256B] at offset 0 (h1 dead after L2's barrier)
#pragma unroll
    for (int m = 0; m < 3; ++m)
#pragma unroll
      for (int j = 0; j < 4; ++j) {
        float v = acc3[m][j] + bias;
        v = v > 0.f ? v : 0.f;
        int rw = m * 16 + lg * 4 + j;
        *(f16*)(lds + rw * 256 + ((n * 2) ^ ((rw & 15) << 4))) = (f16)v;
      }
  }
  __syncthreads();

  // ---------------- L4 + softmax (waves 0..2, 16 rows each) ----------------
  if (wid < 3) {
    f32x4 a4 = (f32x4){0.f, 0.f, 0.f, 0.f};
#pragma unroll
    for (int kc = 0; kc < 4; ++kc) {
      f16x8 Bv = *(const f16x8*)(wpe4 + ln * 256 + kc * 64 + lg * 16);
      f16x8 Av = afrag(lds, 256, wid * 16, kc * 64, lane);
      a4 = MFMA16(Av, Bv, a4);
    }
    float bias = b4[e * D_A + ln];
#pragma unroll
    for (int j = 0; j < 4; ++j) {
      float v = a4[j] + bias;
      float mx = v;
      for (int msk = 8; msk >= 1; msk >>= 1) mx = fmaxf(mx, __shfl_xor(mx, msk));
      float pe = expf(v - mx);
      float sm = pe;
      for (int msk = 8; msk >= 1; msk >>= 1) sm += __shfl_xor(sm, msk);
      int rl = wid * 16 + lg * 4 + j;
      if (rl < rvalid) out[(long)idx[row0 + rl] * D_A + ln] = pe / sm;
    }
  }
}

// ---------------- host ----------------

extern "C" void kernel_launch(void* const* d_in, const int* in_sizes, int n_in,
                              void* d_out, int out_size, void* d_ws, size_t ws_size,
                              hipStream_t stream) {
  const float* x  = (const float*)d_in[0];
  const int* pos  = (const int*)d_in[1];
  const float* W1 = (const float*)d_in[2];
  const float* b1 = (const float*)d_in[3];
  const float* W2 = (const float*)d_in[4];
  const float* b2 = (const float*)d_in[5];
  const float* W3 = (const float*)d_in[6];
  const float* b3 = (const float*)d_in[7];
  const float* W4 = (const float*)d_in[8];
  const float* b4 = (const float*)d_in[9];
  float* out = (float*)d_out;

  int* hdr = (int*)d_ws;
  int* idx = hdr + IDX_OFF;
  char* wp = (char*)d_ws + WP_OFF;

  hipLaunchKernelGGL(k_bucket, dim3(1), dim3(1024), 0, stream, pos, hdr, idx);
  hipLaunchKernelGGL(k_wcvt, dim3(WSLOTS / 256), dim3(256), 0, stream,
                     W1, W2, W3, W4, wp);
  hipLaunchKernelGGL(k_mlp, dim3(NT_GRID), dim3(THREADS), 0, stream,
                     x, b1, b2, b3, b4, hdr, idx, wp, out);
}

// Round 13
// 67.940 us; speedup vs baseline: 1.0132x; 1.0132x over previous
//
#include <hip/hip_runtime.h>

typedef _Float16 f16;
typedef __attribute__((ext_vector_type(8))) _Float16 f16x8;
typedef __attribute__((ext_vector_type(4))) _Float16 f16x4;
typedef __attribute__((ext_vector_type(4))) float f32x4;

#define MFMA16(a, b, c) __builtin_amdgcn_mfma_f32_16x16x32_f16(a, b, c, 0, 0, 0)

#define B_N 16384
#define E_N 9
#define TILE 32
#define NTILE_MAX 520  // = 8*65, bijective XCD swizzle
#define THREADS 512

#define D_IN 512
#define D_H1 512
#define D_H2 256
#define D_H3 128
#define D_A 16

// Weight image (k-major): per (e,w) 104 x 1KB records,
// record r at ((e*8+w)*104+r)*1024, lane l's 16B at +l*16.
//   r<64  (L1): kk=r>>2, nf=r&3:  n=w*64+nf*16+ln, k=kk*32+lg*8
//   64..95(L2): j=r-64,kk=j>>1,nf=j&1: n=w*32+nf*16+ln, k=kk*32+lg*8
//   96..103(L3): kk=r-96:         n=w*16+ln,       k=kk*32+lg*8
// L4: plain [16n][128k] per expert (4KB) at O4B.
#define RPW 104
#define O4B 7667712
#define WPL_BYTES 7704576
#define WSLOTS (WPL_BYTES / 16)

#define IDX_OFF 64
#define WP_OFF 131584

// LDS (bytes): x/h1 [32][1024B] at 0 (swz (row&15)<<4); h2 [32][512B] at 32K;
// h3 [32][256B] overlays offset 0 after L2; ring 8 waves x 3 slots x 1KB at 48K.
#define H2_OFF 32768
#define RING_OFF 49152
#define LDS_BYTES 73728   // x2 = 147456 <= 160KB -> 2 blocks/CU

// ---------------- bucketing ----------------

__global__ void k_bucket(const int* __restrict__ pos, int* __restrict__ hdr,
                         int* __restrict__ idx) {
  __shared__ int cnt[E_N], cur[E_N];
  __shared__ int flag_s;
  const int t = threadIdx.x;  // 1024
  if (t < E_N) cnt[t] = 0;
  if (t == 0) {
    int nz = 0;
    for (int i = 0; i < 64; ++i) nz |= pos[2 * i + 1];
    flag_s = (nz == 0) ? 1 : 0;  // int64 layout if all high words zero
  }
  __syncthreads();
  const bool f64 = flag_s != 0;
  int e[16];
#pragma unroll
  for (int k = 0; k < 16; ++k) {
    int i = k * 1024 + t;
    long long v = f64 ? ((const long long*)pos)[i] : (long long)pos[i];
    v = v < 0 ? 0 : (v > 8 ? 8 : v);
    e[k] = (int)v;
    atomicAdd(&cnt[e[k]], 1);
  }
  __syncthreads();
  if (t == 0) {
    int acc = 0;
    for (int ee = 0; ee < E_N; ++ee) { cur[ee] = acc; acc += cnt[ee]; }
  }
  if (t < E_N) hdr[8 + t] = cnt[t];
  __syncthreads();
#pragma unroll
  for (int k = 0; k < 16; ++k) {
    int i = k * 1024 + t;
    int slot = atomicAdd(&cur[e[k]], 1);
    idx[slot] = i;
  }
}

// ---------------- weight convert fp32 -> k-major fragment image ----------------

__global__ void k_wcvt(const float* __restrict__ W1, const float* __restrict__ W2,
                       const float* __restrict__ W3, const float* __restrict__ W4,
                       char* __restrict__ wp) {
  int slot = blockIdx.x * 256 + threadIdx.x;
  if (slot >= WSLOTS) return;
  long addr = (long)slot << 4;
  int lane = slot & 63;
  int lg = lane >> 4, ln = lane & 15;
  const float* src;
  if (addr < O4B) {
    int rec = (int)(addr >> 10);
    int f = rec % RPW;
    int ew = rec / RPW;
    int w = ew & 7, e = ew >> 3;
    if (f < 64) {
      int kk = f >> 2, nf = f & 3;
      int n = w * 64 + nf * 16 + ln;
      int k = kk * 32 + lg * 8;
      src = W1 + ((long)e * D_H1 + n) * D_IN + k;
    } else if (f < 96) {
      int j = f - 64;
      int kk = j >> 1, nf = j & 1;
      int n = w * 32 + nf * 16 + ln;
      int k = kk * 32 + lg * 8;
      src = W2 + ((long)e * D_H2 + n) * D_H1 + k;
    } else {
      int kk = f - 96;
      int n = w * 16 + ln;
      int k = kk * 32 + lg * 8;
      src = W3 + ((long)e * D_H3 + n) * D_H2 + k;
    }
  } else {
    long rel = addr - O4B;
    int e = (int)(rel >> 12);
    int r2 = (int)(rel & 4095);
    int s = r2 >> 4, n = s >> 4, k16 = s & 15;
    src = W4 + ((long)e * D_A + n) * D_H3 + k16 * 8;
  }
  float4 a = *(const float4*)src;
  float4 b = *(const float4*)(src + 4);
  f16x8 h;
  h[0] = (f16)a.x; h[1] = (f16)a.y; h[2] = (f16)a.z; h[3] = (f16)a.w;
  h[4] = (f16)b.x; h[5] = (f16)b.y; h[6] = (f16)b.z; h[7] = (f16)b.w;
  *(f16x8*)(wp + addr) = h;
}

// ---------------- fused MLP ----------------

__device__ __forceinline__ f16x8 afrag(const char* base, int strideB, int rowoff,
                                       int kbytes, int lane) {
  int m = rowoff + (lane & 15);
  int q = kbytes + ((lane >> 4) * 16);
  return *(const f16x8*)(base + m * strideB + (q ^ ((m & 15) << 4)));
}

// async DMA: per-lane global src; wave-uniform LDS dest (HW adds lane*16).
__device__ __forceinline__ void dma16(const char* g, char* l) {
  __builtin_amdgcn_global_load_lds(
      (const __attribute__((address_space(1))) void*)g,
      (__attribute__((address_space(3))) void*)l, 16, 0, 0);
}

template <int N> __device__ __forceinline__ void waitv();
template <> __device__ __forceinline__ void waitv<2>() {
  asm volatile("s_waitcnt vmcnt(2)" ::: "memory");
}
template <> __device__ __forceinline__ void waitv<1>() {
  asm volatile("s_waitcnt vmcnt(1)" ::: "memory");
}
template <> __device__ __forceinline__ void waitv<0>() {
  asm volatile("s_waitcnt vmcnt(0)" ::: "memory");
}

__launch_bounds__(THREADS, 2)
__global__ void k_mlp(const float* __restrict__ x,
                      const float* __restrict__ b1, const float* __restrict__ b2,
                      const float* __restrict__ b3, const float* __restrict__ b4,
                      const int* __restrict__ hdr, const int* __restrict__ idx,
                      const char* __restrict__ wp, float* __restrict__ out) {
  __shared__ __align__(16) char lds[LDS_BYTES];

  int b = blockIdx.x;
  int bswz = (b & 7) * (NTILE_MAX / 8) + (b >> 3);  // bijective, 520 = 8*65

  const int* counts = hdr + 8;
  int e = -1, tile = 0, base = 0, ne = 0;
  {
    int acc = 0, off = 0;
    for (int ee = 0; ee < E_N; ++ee) {
      int n = counts[ee];
      int nt = (n + TILE - 1) / TILE;
      if (bswz < acc + nt) { e = ee; tile = bswz - acc; ne = n; base = off; break; }
      acc += nt; off += n;
    }
  }
  if (e < 0) return;
  const int rvalid = min(TILE, ne - tile * TILE);
  const int row0 = base + tile * TILE;

  const int t = threadIdx.x;
  const int lane = t & 63;
  const int wid = t >> 6;
  const int lg = lane >> 4;
  const int ln = lane & 15;

  const char* wb = wp + ((long)(e * 8 + wid) * RPW << 10);
  const char* wpe4 = wp + O4B + (long)e * 4096;
  char* ringw = lds + RING_OFF + wid * 3072;  // 3 slots x 1KB, per wave

  // prologue: DMA records 0..2 (drained by the staging barrier)
  dma16(wb + 0 * 1024 + lane * 16, ringw + 0 * 1024);
  dma16(wb + 1 * 1024 + lane * 16, ringw + 1 * 1024);
  dma16(wb + 2 * 1024 + lane * 16, ringw + 2 * 1024);

  // ---- stage x tile as fp16, XOR-swizzled ----
  const float4* x4 = (const float4*)x;
#pragma unroll
  for (int v8 = 0; v8 < 8; ++v8) {
    int u = v8 * THREADS + t;              // 4096 = 32*128 float4s
    int s = u >> 7, c4 = u & 127;
    float4 v = make_float4(0.f, 0.f, 0.f, 0.f);
    if (s < rvalid) v = x4[(long)idx[row0 + s] * (D_IN / 4) + c4];
    f16x4 h;
    h[0] = (f16)v.x; h[1] = (f16)v.y; h[2] = (f16)v.z; h[3] = (f16)v.w;
    *(f16x4*)(lds + s * 1024 + ((c4 * 8) ^ ((s & 15) << 4))) = h;
  }
  __syncthreads();

  // ---------------- L1: h1[32x512] = x @ W1^T (recs 0..63) ----------------
  {
    f32x4 acc[2][4];
#pragma unroll
    for (int m = 0; m < 2; ++m)
#pragma unroll
      for (int nf = 0; nf < 4; ++nf) acc[m][nf] = (f32x4){0.f, 0.f, 0.f, 0.f};

#pragma unroll
    for (int kk = 0; kk < 16; ++kk) {
      f16x8 A0 = afrag(lds, 1024, 0, kk * 64, lane);
      f16x8 A1 = afrag(lds, 1024, 16, kk * 64, lane);
#pragma unroll
      for (int nf = 0; nf < 4; ++nf) {
        const int rec = kk * 4 + nf;
        waitv<2>();  // FIFO: everything except last 2 issued ops has landed
        f16x8 B = *(const f16x8*)(ringw + (rec % 3) * 1024 + lane * 16);
        __builtin_amdgcn_s_setprio(1);
        acc[0][nf] = MFMA16(A0, B, acc[0][nf]);
        acc[1][nf] = MFMA16(A1, B, acc[1][nf]);
        __builtin_amdgcn_s_setprio(0);
        const int nr = rec + 3;  // <= 66: streams into L2 records
        dma16(wb + (long)nr * 1024 + lane * 16, ringw + (nr % 3) * 1024);
      }
    }
    __syncthreads();  // x region dead; barrier drains in-flight DMAs

    // write h1 = relu(acc+bias) into x region [32][1024B]
#pragma unroll
    for (int nf = 0; nf < 4; ++nf) {
      int n = wid * 64 + nf * 16 + ln;
      float bias = b1[e * D_H1 + n];
#pragma unroll
      for (int m = 0; m < 2; ++m)
#pragma unroll
        for (int j = 0; j < 4; ++j) {
          float v = acc[m][nf][j] + bias;
          v = v > 0.f ? v : 0.f;
          int rw = m * 16 + lg * 4 + j;
          *(f16*)(lds + rw * 1024 + ((n * 2) ^ ((rw & 15) << 4))) = (f16)v;
        }
    }
  }
  __syncthreads();

  // ---------------- L2: h2[32x256] = h1 @ W2^T (recs 64..95) ----------------
  {
    f32x4 acc2[2][2];
#pragma unroll
    for (int m = 0; m < 2; ++m)
#pragma unroll
      for (int nf = 0; nf < 2; ++nf) acc2[m][nf] = (f32x4){0.f, 0.f, 0.f, 0.f};

#pragma unroll
    for (int kk = 0; kk < 16; ++kk) {
      f16x8 A0 = afrag(lds, 1024, 0, kk * 64, lane);
      f16x8 A1 = afrag(lds, 1024, 16, kk * 64, lane);
#pragma unroll
      for (int nf = 0; nf < 2; ++nf) {
        const int rec = 64 + kk * 2 + nf;
        waitv<2>();
        f16x8 B = *(const f16x8*)(ringw + (rec % 3) * 1024 + lane * 16);
        __builtin_amdgcn_s_setprio(1);
        acc2[0][nf] = MFMA16(A0, B, acc2[0][nf]);
        acc2[1][nf] = MFMA16(A1, B, acc2[1][nf]);
        __builtin_amdgcn_s_setprio(0);
        const int nr = rec + 3;  // <= 98
        dma16(wb + (long)nr * 1024 + lane * 16, ringw + (nr % 3) * 1024);
      }
    }
    // h2 region dedicated: direct write
#pragma unroll
    for (int nf = 0; nf < 2; ++nf) {
      int n = wid * 32 + nf * 16 + ln;
      float bias = b2[e * D_H2 + n];
#pragma unroll
      for (int m = 0; m < 2; ++m)
#pragma unroll
        for (int j = 0; j < 4; ++j) {
          float v = acc2[m][nf][j] + bias;
          v = v > 0.f ? v : 0.f;
          int rw = m * 16 + lg * 4 + j;
          *(f16*)(lds + H2_OFF + rw * 512 + ((n * 2) ^ ((rw & 15) << 4))) = (f16)v;
        }
    }
  }
  __syncthreads();  // drains DMAs for recs 96..98

  // ---------------- L3: h3[32x128] = h2 @ W3^T (recs 96..103) ----------------
  // Steps issue the remaining stream (99..103) with literal wait counts.
  {
    f32x4 acc3[2];
    acc3[0] = (f32x4){0.f, 0.f, 0.f, 0.f};
    acc3[1] = (f32x4){0.f, 0.f, 0.f, 0.f};

#define L3STEP(REC, WAITN)                                                     \
  {                                                                            \
    const int kk3 = (REC) - 96;                                                \
    f16x8 A0 = afrag(lds + H2_OFF, 512, 0, kk3 * 64, lane);                    \
    f16x8 A1 = afrag(lds + H2_OFF, 512, 16, kk3 * 64, lane);                   \
    waitv<WAITN>();                                                            \
    f16x8 B = *(const f16x8*)(ringw + ((REC) % 3) * 1024 + lane * 16);         \
    __builtin_amdgcn_s_setprio(1);                                             \
    acc3[0] = MFMA16(A0, B, acc3[0]);                                          \
    acc3[1] = MFMA16(A1, B, acc3[1]);                                          \
    __builtin_amdgcn_s_setprio(0);                                             \
    if ((REC) + 3 <= 103)                                                      \
      dma16(wb + (long)((REC) + 3) * 1024 + lane * 16,                         \
            ringw + (((REC) + 3) % 3) * 1024);                                 \
  }

    L3STEP(96, 2)
    L3STEP(97, 2)
    L3STEP(98, 2)
    L3STEP(99, 2)
    L3STEP(100, 2)
    L3STEP(101, 2)
    L3STEP(102, 1)
    L3STEP(103, 0)
#undef L3STEP

    int n = wid * 16 + ln;
    float bias = b3[e * D_H3 + n];
    // h3 [32][256B] at offset 0 (x/h1 dead after the post-L2 barrier)
#pragma unroll
    for (int m = 0; m < 2; ++m)
#pragma unroll
      for (int j = 0; j < 4; ++j) {
        float v = acc3[m][j] + bias;
        v = v > 0.f ? v : 0.f;
        int rw = m * 16 + lg * 4 + j;
        *(f16*)(lds + rw * 256 + ((n * 2) ^ ((rw & 15) << 4))) = (f16)v;
      }
  }
  __syncthreads();

  // ---------------- L4 + softmax (waves 0,1; 16 rows each) ----------------
  if (wid < 2) {
    f32x4 a4 = (f32x4){0.f, 0.f, 0.f, 0.f};
#pragma unroll
    for (int kc = 0; kc < 4; ++kc) {
      f16x8 Bv = *(const f16x8*)(wpe4 + ln * 256 + kc * 64 + lg * 16);
      f16x8 Av = afrag(lds, 256, wid * 16, kc * 64, lane);
      a4 = MFMA16(Av, Bv, a4);
    }
    float bias = b4[e * D_A + ln];
#pragma unroll
    for (int j = 0; j < 4; ++j) {
      float v = a4[j] + bias;
      float mx = v;
      for (int msk = 8; msk >= 1; msk >>= 1) mx = fmaxf(mx, __shfl_xor(mx, msk));
      float pe = expf(v - mx);
      float sm = pe;
      for (int msk = 8; msk >= 1; msk >>= 1) sm += __shfl_xor(sm, msk);
      int rl = wid * 16 + lg * 4 + j;
      if (rl < rvalid) out[(long)idx[row0 + rl] * D_A + ln] = pe / sm;
    }
  }
}

// ---------------- host ----------------

extern "C" void kernel_launch(void* const* d_in, const int* in_sizes, int n_in,
                              void* d_out, int out_size, void* d_ws, size_t ws_size,
                              hipStream_t stream) {
  const float* x  = (const float*)d_in[0];
  const int* pos  = (const int*)d_in[1];
  const float* W1 = (const float*)d_in[2];
  const float* b1 = (const float*)d_in[3];
  const float* W2 = (const float*)d_in[4];
  const float* b2 = (const float*)d_in[5];
  const float* W3 = (const float*)d_in[6];
  const float* b3 = (const float*)d_in[7];
  const float* W4 = (const float*)d_in[8];
  const float* b4 = (const float*)d_in[9];
  float* out = (float*)d_out;

  int* hdr = (int*)d_ws;
  int* idx = hdr + IDX_OFF;
  char* wp = (char*)d_ws + WP_OFF;

  hipLaunchKernelGGL(k_bucket, dim3(1), dim3(1024), 0, stream, pos, hdr, idx);
  hipLaunchKernelGGL(k_wcvt, dim3(WSLOTS / 256), dim3(256), 0, stream,
                     W1, W2, W3, W4, wp);
  hipLaunchKernelGGL(k_mlp, dim3(NTILE_MAX), dim3(THREADS), 0, stream,
                     x, b1, b2, b3, b4, hdr, idx, wp, out);
}